// Round 1
// baseline (43365.048 us; speedup 1.0000x reference)
//
#include <hip/hip_runtime.h>

// ---------------------------------------------------------------------------
// 2-layer LSTM (B=256, T=784, H=512, C=10), persistent-kernel design.
//
// Grid = 256 WGs x 256 threads, one WG per CU (forced by 128KiB dynamic LDS),
// so all WGs are co-resident and a hand-rolled device-scope barrier is safe.
//
// WG 0..127   ("L1"): owns layer-1 gates for (row-block rb of 64 batch rows,
//                      j-slice js of 16 hidden cols, all 4 gates i/f/g/o).
//                      W_hh1 slice in LDS (bf16, XOR-swizzled). c1 in regs.
//                      Also computes the final FC (out = h2 @ W_fc^T + b_fc)
//                      during phase B (lagged by one step).
// WG 128..255 ("L2"): owns layer-2 gates for same (rb, js) mapping.
//                      W_hh2 + W_ih2 slices in LDS. c2 in regs.
//
// Per step t:
//   phase A: L1: gates1 = h1@W_hh1^T (+x*W_ih1+b), cell1 -> write h1,c1 (bf16)
//            L2: accG = h2@W_hh2^T (kept in registers)
//   sync1
//   phase B: L2: accG += c1@W_ih2^T (+b), cell2 -> write h2 (bf16)
//            L1: out[:, t-1] = h2(t-1) @ W_fc^T + b_fc
//   sync2
//
// Sync = per-WG monotonic flags (release store, agent scope) + wave0 polls
// all 256 flags with relaxed agent loads; asymmetric targets give cross-step
// pipelining between L1 and L2 WGs.
// ---------------------------------------------------------------------------

constexpr int Bn = 256;   // batch
constexpr int Tn = 784;   // timesteps
constexpr int Hn = 512;   // hidden
constexpr int Cn = 10;    // classes

typedef short s16x8 __attribute__((ext_vector_type(8)));
typedef float f32x4 __attribute__((ext_vector_type(4)));

__device__ __forceinline__ unsigned short f2bf(float f) {
  unsigned u = __float_as_uint(f);
  u += 0x7FFFu + ((u >> 16) & 1u);  // round-to-nearest-even
  return (unsigned short)(u >> 16);
}
__device__ __forceinline__ float bf2f(unsigned short s) {
  return __uint_as_float(((unsigned)s) << 16);
}
__device__ __forceinline__ float sigm(float v) { return 1.f / (1.f + __expf(-v)); }
__device__ __forceinline__ float tanh_(float v) {
  float vc = fminf(fmaxf(v, -15.f), 15.f);
  float e = __expf(2.f * vc);
  return (e - 1.f) / (e + 1.f);
}

// Arrive: publish my flag value (release makes all prior global stores visible
// device-wide before the flag lands).
__device__ __forceinline__ void arrive_flag(unsigned* flags, int wg, unsigned val) {
  __syncthreads();  // all waves' stores drained (syncthreads implies vmcnt(0))
  if (threadIdx.x == 0)
    __hip_atomic_store(&flags[wg], val, __ATOMIC_RELEASE, __HIP_MEMORY_SCOPE_AGENT);
}

// Wait until min(L1 flags) >= t1 and min(L2 flags) >= t2. Wave 0 polls,
// other waves park at syncthreads. Acquire fence after.
__device__ __forceinline__ void wait_flags(unsigned* flags, unsigned t1, unsigned t2) {
  if ((threadIdx.x >> 6) == 0) {
    const int l = threadIdx.x & 63;
    int guard = 0;
    for (;;) {
      unsigned a = __hip_atomic_load(&flags[l],       __ATOMIC_RELAXED, __HIP_MEMORY_SCOPE_AGENT);
      unsigned b = __hip_atomic_load(&flags[l + 64],  __ATOMIC_RELAXED, __HIP_MEMORY_SCOPE_AGENT);
      unsigned c = __hip_atomic_load(&flags[l + 128], __ATOMIC_RELAXED, __HIP_MEMORY_SCOPE_AGENT);
      unsigned d = __hip_atomic_load(&flags[l + 192], __ATOMIC_RELAXED, __HIP_MEMORY_SCOPE_AGENT);
      bool ok = (a >= t1) && (b >= t1) && (c >= t2) && (d >= t2);
      if (__all(ok)) break;
      if (++guard > (1 << 17)) break;  // safety valve against hard hang
      __builtin_amdgcn_s_sleep(1);
    }
  }
  __syncthreads();
  __threadfence();  // acquire: invalidate so subsequent reads see fresh data
}

// One 64x(4x16) gate-GEMM slice, K=512, via 16x16x32 bf16 MFMA.
// A: state rows from global bf16 (Abase already = row*H + (l>>4)*8).
// B: weight slice from LDS (16B-chunk XOR swizzle on row&7).
__device__ __forceinline__ void gemm_slice(const unsigned short* __restrict__ Abase,
                                           const char* smem, int ldsbase,
                                           f32x4* acc, int l) {
  const int lg = l >> 4, rA = l & 15, lx = l & 7;
  s16x8 af[16];
#pragma unroll
  for (int kc = 0; kc < 16; ++kc)
    af[kc] = *(const s16x8*)(Abase + kc * 32);
#pragma unroll
  for (int kc = 0; kc < 16; ++kc) {
#pragma unroll
    for (int g = 0; g < 4; ++g) {
      int byte = ldsbase + (((g << 4) + rA) << 10) + ((((kc << 2) + lg) ^ lx) << 4);
      s16x8 bf = *(const s16x8*)(smem + byte);
      acc[g] = __builtin_amdgcn_mfma_f32_16x16x32_bf16(af[kc], bf, acc[g], 0, 0, 0);
    }
  }
}

// Final FC for one timestep column: out[b, tt, :] from h2buf (bf16, one parity
// slab). Each L1-WG covers 2 batch rows; per wave: one row, 5 classes.
__device__ __forceinline__ void out_duty(int tt, int sub, int wv, int l,
                                         const unsigned short* __restrict__ h2buf,
                                         const char* smem, float* __restrict__ out) {
  const int b = (sub << 1) + (wv >> 1);
  const int cg = (wv & 1) * 5;
  s16x8 h8 = *(const s16x8*)(h2buf + (size_t)b * Hn + (l << 3));
  const unsigned short* wf = (const unsigned short*)(smem + 65536);
  float rs[5];
#pragma unroll
  for (int c5 = 0; c5 < 5; ++c5) {
    s16x8 w8 = *(const s16x8*)(wf + (size_t)(cg + c5) * Hn + (l << 3));
    float s = 0.f;
#pragma unroll
    for (int i = 0; i < 8; ++i)
      s += bf2f((unsigned short)h8[i]) * bf2f((unsigned short)w8[i]);
    rs[c5] = s;
  }
#pragma unroll
  for (int c5 = 0; c5 < 5; ++c5) {
#pragma unroll
    for (int off = 32; off > 0; off >>= 1)
      rs[c5] += __shfl_xor(rs[c5], off);
  }
  if (l < 5) {
    float v = (l == 0) ? rs[0] : (l == 1) ? rs[1] : (l == 2) ? rs[2] : (l == 3) ? rs[3] : rs[4];
    v += ((const float*)(smem + 65536 + Cn * Hn * 2))[cg + l];
    out[(size_t)b * (Tn * Cn) + (size_t)tt * Cn + (cg + l)] = v;
  }
}

__global__ void __launch_bounds__(256, 1)
lstm2_kernel(const float* __restrict__ x,
             const float* __restrict__ W_ih1, const float* __restrict__ W_hh1,
             const float* __restrict__ b_ih1, const float* __restrict__ b_hh1,
             const float* __restrict__ W_ih2, const float* __restrict__ W_hh2,
             const float* __restrict__ b_ih2, const float* __restrict__ b_hh2,
             const float* __restrict__ W_fc, const float* __restrict__ b_fc,
             float* __restrict__ out,
             unsigned* __restrict__ flags,
             unsigned short* __restrict__ h1b,   // [2][B][H] bf16 (double buf)
             unsigned short* __restrict__ c1b,   // [2][B][H] bf16 (double buf)
             unsigned short* __restrict__ h2b)   // [2][B][H] bf16 (double buf)
{
  extern __shared__ char smem[];
  const int tid = threadIdx.x;
  const int wg = blockIdx.x;
  const int wv = tid >> 6;
  const int l = tid & 63;
  const bool isL1 = (wg < 128);
  const int sub = isL1 ? wg : (wg - 128);
  const int rb = (sub >> 5) << 6;   // 0,64,128,192
  const int js = (sub & 31) << 4;   // 0..496

  // ---- one-time: weight slices -> LDS bf16, XOR-swizzled on 16B chunks ----
  {
    const float* W0 = isL1 ? W_hh1 : W_hh2;
    for (int idx = tid * 4; idx < 64 * 512; idx += 1024) {
      int row = idx >> 9, k = idx & 511;                    // row = g*16 + c
      int n = ((row >> 4) << 9) + js + (row & 15);          // gate col in [0,2048)
      float4 w = *(const float4*)(W0 + (size_t)n * Hn + k);
      short4 v = { (short)f2bf(w.x), (short)f2bf(w.y), (short)f2bf(w.z), (short)f2bf(w.w) };
      int byte = (row << 10) + ((((k >> 3) ^ (row & 7)) << 4)) + ((k & 7) << 1);
      *(short4*)(smem + byte) = v;
    }
    if (!isL1) {
      for (int idx = tid * 4; idx < 64 * 512; idx += 1024) {
        int row = idx >> 9, k = idx & 511;
        int n = ((row >> 4) << 9) + js + (row & 15);
        float4 w = *(const float4*)(W_ih2 + (size_t)n * Hn + k);
        short4 v = { (short)f2bf(w.x), (short)f2bf(w.y), (short)f2bf(w.z), (short)f2bf(w.w) };
        int byte = 65536 + (row << 10) + ((((k >> 3) ^ (row & 7)) << 4)) + ((k & 7) << 1);
        *(short4*)(smem + byte) = v;
      }
    } else {
      unsigned short* wf = (unsigned short*)(smem + 65536);
      for (int idx = tid; idx < Cn * Hn; idx += 256) wf[idx] = f2bf(W_fc[idx]);
      if (tid < Cn) ((float*)(smem + 65536 + Cn * Hn * 2))[tid] = b_fc[tid];
    }
  }
  __syncthreads();

  // per-lane constants: input-proj weights and fused biases for my 4 gate cols
  float wih1g[4], b1g[4], b2g[4];
  {
    int col = js + (l & 15);
#pragma unroll
    for (int g = 0; g < 4; ++g) {
      int n = (g << 9) + col;
      if (isL1) { wih1g[g] = W_ih1[n]; b1g[g] = b_ih1[n] + b_hh1[n]; b2g[g] = 0.f; }
      else      { wih1g[g] = 0.f;      b1g[g] = 0.f;                 b2g[g] = b_ih2[n] + b_hh2[n]; }
    }
  }

  const int rA = l & 15, lg = l >> 4;
  const int arow = rb + (wv << 4) + rA;           // A-fragment row (batch)
  const int myrow = rb + (wv << 4) + (lg << 2);   // C/D first row (batch)
  const int colj = js + rA;                       // my hidden col

  float cst[4] = {0.f, 0.f, 0.f, 0.f};  // persistent cell state (c1 or c2)
  unsigned fv = 0;

  for (int t = 0; t < Tn; ++t) {
    const int wb = t & 1, rbf = wb ^ 1;
    f32x4 acc[4];
#pragma unroll
    for (int g = 0; g < 4; ++g) acc[g] = f32x4{0.f, 0.f, 0.f, 0.f};

    // ---------------- phase A ----------------
    if (isL1) {
      float xv[4];
#pragma unroll
      for (int r = 0; r < 4; ++r) xv[r] = x[(size_t)(myrow + r) * Tn + t];
      gemm_slice(h1b + (size_t)rbf * Bn * Hn + (size_t)arow * Hn + (lg << 3), smem, 0, acc, l);
      unsigned short* h1w = h1b + (size_t)wb * Bn * Hn;
      unsigned short* c1w = c1b + (size_t)wb * Bn * Hn;
#pragma unroll
      for (int r = 0; r < 4; ++r) {
        float iv = sigm(acc[0][r] + xv[r] * wih1g[0] + b1g[0]);
        float ff = sigm(acc[1][r] + xv[r] * wih1g[1] + b1g[1]);
        float gv = tanh_(acc[2][r] + xv[r] * wih1g[2] + b1g[2]);
        float ov = sigm(acc[3][r] + xv[r] * wih1g[3] + b1g[3]);
        float c = ff * cst[r] + iv * gv;
        cst[r] = c;
        float h = ov * tanh_(c);
        size_t off = (size_t)(myrow + r) * Hn + colj;
        h1w[off] = f2bf(h);
        c1w[off] = f2bf(c);
      }
    } else {
      // recurrent part of layer-2 gates (uses h2 from t-1); kept in acc regs
      gemm_slice(h2b + (size_t)rbf * Bn * Hn + (size_t)arow * Hn + (lg << 3), smem, 0, acc, l);
    }

    // sync1 (flag value 2t+1)
    ++fv; arrive_flag(flags, wg, fv);
    if (isL1) wait_flags(flags, 0u, (unsigned)(2 * t));        // h2(t-1) for out_duty
    else      wait_flags(flags, (unsigned)(2 * t + 1), 0u);    // c1(t) ready

    // ---------------- phase B ----------------
    if (isL1) {
      if (t > 0)
        out_duty(t - 1, sub, wv, l, h2b + (size_t)((t - 1) & 1) * Bn * Hn, smem, out);
    } else {
      gemm_slice(c1b + (size_t)wb * Bn * Hn + (size_t)arow * Hn + (lg << 3), smem, 65536, acc, l);
      unsigned short* h2w = h2b + (size_t)wb * Bn * Hn;
#pragma unroll
      for (int r = 0; r < 4; ++r) {
        float iv = sigm(acc[0][r] + b2g[0]);
        float ff = sigm(acc[1][r] + b2g[1]);
        float gv = tanh_(acc[2][r] + b2g[2]);
        float ov = sigm(acc[3][r] + b2g[3]);
        float c = ff * cst[r] + iv * gv;
        cst[r] = c;
        float h = ov * tanh_(c);
        h2w[(size_t)(myrow + r) * Hn + colj] = f2bf(h);
      }
    }

    // sync2 (flag value 2t+2)
    ++fv; arrive_flag(flags, wg, fv);
    if (isL1) wait_flags(flags, fv, (unsigned)(2 * t));  // all L1 done (h1 ready); L2 past B(t-1) (c1 parity safe)
    else      wait_flags(flags, 0u, fv);                 // all L2 done (h2 ready)
  }

  // epilogue: out[:, T-1]
  if (isL1) {
    wait_flags(flags, 0u, (unsigned)(2 * Tn));
    out_duty(Tn - 1, sub, wv, l, h2b + (size_t)((Tn - 1) & 1) * Bn * Hn, smem, out);
  }
}

extern "C" void kernel_launch(void* const* d_in, const int* in_sizes, int n_in,
                              void* d_out, int out_size, void* d_ws, size_t ws_size,
                              hipStream_t stream) {
  const float* x     = (const float*)d_in[0];
  const float* W_ih1 = (const float*)d_in[1];
  const float* W_hh1 = (const float*)d_in[2];
  const float* b_ih1 = (const float*)d_in[3];
  const float* b_hh1 = (const float*)d_in[4];
  const float* W_ih2 = (const float*)d_in[5];
  const float* W_hh2 = (const float*)d_in[6];
  const float* b_ih2 = (const float*)d_in[7];
  const float* b_hh2 = (const float*)d_in[8];
  const float* W_fc  = (const float*)d_in[9];
  const float* b_fc  = (const float*)d_in[10];
  float* out = (float*)d_out;

  unsigned* flags = (unsigned*)d_ws;
  unsigned short* h1b = (unsigned short*)((char*)d_ws + 4096);
  unsigned short* c1b = h1b + 2 * Bn * Hn;
  unsigned short* h2b = c1b + 2 * Bn * Hn;

  // zero flags + state buffers every launch (graph-replay safe, deterministic)
  hipMemsetAsync(d_ws, 0, 4096 + (size_t)3 * 2 * Bn * Hn * sizeof(unsigned short), stream);

  (void)hipFuncSetAttribute((const void*)lstm2_kernel,
                            hipFuncAttributeMaxDynamicSharedMemorySize, 131072);

  lstm2_kernel<<<dim3(256), dim3(256), 131072, stream>>>(
      x, W_ih1, W_hh1, b_ih1, b_hh1, W_ih2, W_hh2, b_ih2, b_hh2, W_fc, b_fc,
      out, flags, h1b, c1b, h2b);
}

// Round 3
// 10514.294 us; speedup vs baseline: 4.1244x; 4.1244x over previous
//
#include <hip/hip_runtime.h>

// ---------------------------------------------------------------------------
// 2-layer LSTM (B=256, T=784, H=512, C=10), persistent kernel, round 3.
//
// Round-1: passed, 43 ms. Sync via release-store + __threadfence (L2 inv)
//          pushed all state to HBM every step -> latency-bound (MfmaUtil 1%).
// Round-2: sc0/sc1 cache-bypass slabs + relaxed flags. FAILED (absmax 6e-2):
//          arrive() relied on __syncthreads to drain vmem, but the slab
//          stores are inline asm -> compiler's pre-barrier waitcnt doesn't
//          cover them -> flag could publish before data stores landed.
// Round-3 fix: every wave drains vmcnt(0) explicitly (HW counter covers asm
//          stores) before the barrier; lane-0 publishes with RELEASE (agent).
//          Release's buffer_wbl2 is now cheap: slab stores are write-through,
//          so the only dirty L2 lines are the tiny `out` writes.
//
// Structure (unchanged from round 2):
//   WG 0..127  (L1): layer-1 cell for (rb: 64 batch rows, js: 16 hidden cols,
//                    all 4 gates). W_hh1 slice in LDS (XOR-swizzled).
//                    c1 in registers. Phase B: FC output for step t-1.
//   WG 128..255(L2): layer-2. W_hh2 + W_ih2 slices in LDS. c2 in registers.
//   Group-local sync: 4 groups of (32 L1 + 32 L2) WGs; each WG polls only
//   its group's 32 producer flags. One arrive per WG per step:
//     L1 publishes a1=t+1 after phase A; L2 publishes a2=t+1 after phase B.
//
// Dependency proof (parity p = t&1):
//   L1-A(t): reads h1[1-p] (A(t-1): a1>=t), writes h1[p] (last read A(t-1):
//            a1>=t), writes c1[p] (last read L2-B(t-2): a2>=t-1).
//   L1-B(t): out_duty(t-1) reads h2[(t-1)&1] (L2-B(t-1): a2>=t).
//   L2-A(t): reads h2[1-p] (L2-B(t-1): a2>=t).
//   L2-B(t): reads c1[p] (L1-A(t): a1>=t+1); writes h2[p] (last readers:
//            L2-A(t-1) -- ordered by peers' a2>=t publish after B(t-1) which
//            follows A(t-1); L1-B(t-2)'s out_duty -- ordered because a1>=t+1
//            is published after A(t), which follows B(t-1)=out_duty(t-2)).
// ---------------------------------------------------------------------------

constexpr int Bn = 256;   // batch
constexpr int Tn = 784;   // timesteps
constexpr int Hn = 512;   // hidden
constexpr int Cn = 10;    // classes

typedef short s16x8 __attribute__((ext_vector_type(8)));
typedef float f32x4 __attribute__((ext_vector_type(4)));

__device__ __forceinline__ unsigned short f2bf(float f) {
  unsigned u = __float_as_uint(f);
  u += 0x7FFFu + ((u >> 16) & 1u);  // round-to-nearest-even
  return (unsigned short)(u >> 16);
}
__device__ __forceinline__ float bf2f(unsigned short s) {
  return __uint_as_float(((unsigned)s) << 16);
}
__device__ __forceinline__ float sigm(float v) { return 1.f / (1.f + __expf(-v)); }
__device__ __forceinline__ float tanh_(float v) {
  float vc = fminf(fmaxf(v, -15.f), 15.f);
  float e = __expf(2.f * vc);
  return (e - 1.f) / (e + 1.f);
}

// ---- system-scope (cache-bypassing) slab accessors ----
__device__ __forceinline__ s16x8 load16_sc(const unsigned short* p) {
  s16x8 r;
  asm volatile("global_load_dwordx4 %0, %1, off sc0 sc1"
               : "=v"(r) : "v"(p) : "memory");
  return r;
}
__device__ __forceinline__ void store2_sc(unsigned short* p, unsigned short v) {
  unsigned w = v;
  asm volatile("global_store_short %0, %1, off sc0 sc1"
               :: "v"(p), "v"(w) : "memory");
}
// Drain all outstanding vmem (HW counter covers inline-asm ops too) and pin
// scheduling so nothing is hoisted above the wait (guide rule #18).
__device__ __forceinline__ void vm0_fence() {
  asm volatile("s_waitcnt vmcnt(0)" ::: "memory");
  __builtin_amdgcn_sched_barrier(0);
}

// ---- flags ----
// arrive: EVERY wave drains its own vmem (asm sc-stores included) before the
// barrier; after the barrier lane 0 publishes with RELEASE (agent scope).
__device__ __forceinline__ void arrive(unsigned* slot, unsigned v) {
  vm0_fence();
  __syncthreads();
  if (threadIdx.x == 0)
    __hip_atomic_store(slot, v, __ATOMIC_RELEASE, __HIP_MEMORY_SCOPE_AGENT);
}
// wait: wave0 lanes 0..31 poll setA >= thA, lanes 32..63 poll setB >= thB.
__device__ __forceinline__ void wait2(const unsigned* setA, int thA,
                                      const unsigned* setB, int thB) {
  if ((threadIdx.x >> 6) == 0) {
    const int l = threadIdx.x & 63;
    const unsigned* p = (l < 32) ? (setA + l) : (setB + (l - 32));
    const int th = (l < 32) ? thA : thB;
    int guard = 0;
    for (;;) {
      int v = (th <= 0) ? th
            : (int)__hip_atomic_load(p, __ATOMIC_RELAXED, __HIP_MEMORY_SCOPE_AGENT);
      if (__all(v >= th)) break;
      if (++guard > (1 << 18)) break;  // deadlock escape only; never legit
      __builtin_amdgcn_s_sleep(1);
    }
  }
  __syncthreads();
}

// One 64x(4x16) gate-GEMM slice, K=512, 16x16x32 bf16 MFMA.
// A: state rows via sc-bypass loads. B: weight slice in LDS (XOR swizzle).
__device__ __forceinline__ void gemm_slice(const unsigned short* __restrict__ Abase,
                                           const char* smem, int ldsbase,
                                           f32x4* acc, int l) {
  const int lg = l >> 4, rA = l & 15, lx = l & 7;
  s16x8 af[16];
#pragma unroll
  for (int kc = 0; kc < 16; ++kc)
    af[kc] = load16_sc(Abase + kc * 32);
  vm0_fence();
#pragma unroll
  for (int kc = 0; kc < 16; ++kc) {
#pragma unroll
    for (int g = 0; g < 4; ++g) {
      int byte = ldsbase + (((g << 4) + rA) << 10) + ((((kc << 2) + lg) ^ lx) << 4);
      s16x8 bf = *(const s16x8*)(smem + byte);
      acc[g] = __builtin_amdgcn_mfma_f32_16x16x32_bf16(af[kc], bf, acc[g], 0, 0, 0);
    }
  }
}

// Final FC for one timestep column (runs on L1 WGs, lagged one step).
__device__ __forceinline__ void out_duty(int tt, int sub, int wv, int l,
                                         const unsigned short* __restrict__ h2buf,
                                         const char* smem, float* __restrict__ out) {
  const int b = (sub << 1) + (wv >> 1);
  const int cg = (wv & 1) * 5;
  s16x8 h8 = load16_sc(h2buf + (size_t)b * Hn + (l << 3));
  vm0_fence();
  const unsigned short* wf = (const unsigned short*)(smem + 65536);
  float rs[5];
#pragma unroll
  for (int c5 = 0; c5 < 5; ++c5) {
    s16x8 w8 = *(const s16x8*)(wf + (size_t)(cg + c5) * Hn + (l << 3));
    float s = 0.f;
#pragma unroll
    for (int i = 0; i < 8; ++i)
      s += bf2f((unsigned short)h8[i]) * bf2f((unsigned short)w8[i]);
    rs[c5] = s;
  }
#pragma unroll
  for (int c5 = 0; c5 < 5; ++c5) {
#pragma unroll
    for (int off = 32; off > 0; off >>= 1)
      rs[c5] += __shfl_xor(rs[c5], off);
  }
  if (l < 5) {
    float v = (l == 0) ? rs[0] : (l == 1) ? rs[1] : (l == 2) ? rs[2] : (l == 3) ? rs[3] : rs[4];
    v += ((const float*)(smem + 65536 + Cn * Hn * 2))[cg + l];
    out[(size_t)b * (Tn * Cn) + (size_t)tt * Cn + (cg + l)] = v;
  }
}

__global__ void __launch_bounds__(256, 1)
lstm2_kernel(const float* __restrict__ x,
             const float* __restrict__ W_ih1, const float* __restrict__ W_hh1,
             const float* __restrict__ b_ih1, const float* __restrict__ b_hh1,
             const float* __restrict__ W_ih2, const float* __restrict__ W_hh2,
             const float* __restrict__ b_ih2, const float* __restrict__ b_hh2,
             const float* __restrict__ W_fc, const float* __restrict__ b_fc,
             float* __restrict__ out,
             unsigned* __restrict__ flags,
             unsigned short* __restrict__ h1b,   // [2][B][H] bf16
             unsigned short* __restrict__ c1b,   // [2][B][H] bf16
             unsigned short* __restrict__ h2b)   // [2][B][H] bf16
{
  extern __shared__ char smem[];
  const int tid = threadIdx.x;
  const int wg = blockIdx.x;
  const int wv = tid >> 6;
  const int l = tid & 63;
  const bool isL1 = (wg < 128);
  const int sub = isL1 ? wg : (wg - 128);
  const int rb = (sub >> 5) << 6;   // 0,64,128,192
  const int js = (sub & 31) << 4;   // 0..496

  // ---- one-time: weight slices -> LDS bf16, XOR-swizzled on 16B chunks ----
  {
    const float* W0 = isL1 ? W_hh1 : W_hh2;
    for (int idx = tid * 4; idx < 64 * 512; idx += 1024) {
      int row = idx >> 9, k = idx & 511;                    // row = g*16 + c
      int n = ((row >> 4) << 9) + js + (row & 15);          // gate col
      float4 w = *(const float4*)(W0 + (size_t)n * Hn + k);
      short4 v = { (short)f2bf(w.x), (short)f2bf(w.y), (short)f2bf(w.z), (short)f2bf(w.w) };
      int byte = (row << 10) + ((((k >> 3) ^ (row & 7)) << 4)) + ((k & 7) << 1);
      *(short4*)(smem + byte) = v;
    }
    if (!isL1) {
      for (int idx = tid * 4; idx < 64 * 512; idx += 1024) {
        int row = idx >> 9, k = idx & 511;
        int n = ((row >> 4) << 9) + js + (row & 15);
        float4 w = *(const float4*)(W_ih2 + (size_t)n * Hn + k);
        short4 v = { (short)f2bf(w.x), (short)f2bf(w.y), (short)f2bf(w.z), (short)f2bf(w.w) };
        int byte = 65536 + (row << 10) + ((((k >> 3) ^ (row & 7)) << 4)) + ((k & 7) << 1);
        *(short4*)(smem + byte) = v;
      }
    } else {
      unsigned short* wf = (unsigned short*)(smem + 65536);
      for (int idx = tid; idx < Cn * Hn; idx += 256) wf[idx] = f2bf(W_fc[idx]);
      if (tid < Cn) ((float*)(smem + 65536 + Cn * Hn * 2))[tid] = b_fc[tid];
    }
  }
  __syncthreads();

  // per-lane constants
  float wih1g[4], b1g[4], b2g[4];
  {
    int col = js + (l & 15);
#pragma unroll
    for (int g = 0; g < 4; ++g) {
      int n = (g << 9) + col;
      if (isL1) { wih1g[g] = W_ih1[n]; b1g[g] = b_ih1[n] + b_hh1[n]; b2g[g] = 0.f; }
      else      { wih1g[g] = 0.f;      b1g[g] = 0.f;                 b2g[g] = b_ih2[n] + b_hh2[n]; }
    }
  }

  const int rA = l & 15, lg = l >> 4;
  const int arow = rb + (wv << 4) + rA;           // A-fragment row (batch)
  const int myrow = rb + (wv << 4) + (lg << 2);   // C/D first row (batch)
  const int colj = js + rA;                       // my hidden col

  unsigned* a1 = flags;         // [128] L1 arrivals (a1[sub] = t+1 after A(t))
  unsigned* a2 = flags + 128;   // [128] L2 arrivals (a2[sub] = t+1 after B(t))
  const int g4 = sub >> 5;
  const unsigned* a1g = a1 + g4 * 32;
  const unsigned* a2g = a2 + g4 * 32;

  float cst[4] = {0.f, 0.f, 0.f, 0.f};  // persistent cell state (c1 or c2)

  for (int t = 0; t < Tn; ++t) {
    const int wb = t & 1, rbf = wb ^ 1;
    f32x4 acc[4];
#pragma unroll
    for (int g = 0; g < 4; ++g) acc[g] = f32x4{0.f, 0.f, 0.f, 0.f};

    if (isL1) {
      // -------- phase A: layer-1 cell --------
      wait2(a1g, t, a2g, t - 1);
      float xv[4];
#pragma unroll
      for (int r = 0; r < 4; ++r) xv[r] = x[(size_t)(myrow + r) * Tn + t];
      gemm_slice(h1b + (size_t)rbf * Bn * Hn + (size_t)arow * Hn + (lg << 3), smem, 0, acc, l);
      unsigned short* h1w = h1b + (size_t)wb * Bn * Hn;
      unsigned short* c1w = c1b + (size_t)wb * Bn * Hn;
#pragma unroll
      for (int r = 0; r < 4; ++r) {
        float iv = sigm(acc[0][r] + xv[r] * wih1g[0] + b1g[0]);
        float ff = sigm(acc[1][r] + xv[r] * wih1g[1] + b1g[1]);
        float gv = tanh_(acc[2][r] + xv[r] * wih1g[2] + b1g[2]);
        float ov = sigm(acc[3][r] + xv[r] * wih1g[3] + b1g[3]);
        float c = ff * cst[r] + iv * gv;
        cst[r] = c;
        float h = ov * tanh_(c);
        size_t off = (size_t)(myrow + r) * Hn + colj;
        store2_sc(h1w + off, f2bf(h));
        store2_sc(c1w + off, f2bf(c));
      }
      arrive(&a1[sub], (unsigned)(t + 1));
      // -------- phase B: FC for step t-1 --------
      wait2(a2g, t, a2g, t);
      if (t > 0)
        out_duty(t - 1, sub, wv, l, h2b + (size_t)((t - 1) & 1) * Bn * Hn, smem, out);
    } else {
      // -------- phase A: h2 @ W_hh2^T --------
      wait2(a2g, t, a2g, t);
      gemm_slice(h2b + (size_t)rbf * Bn * Hn + (size_t)arow * Hn + (lg << 3), smem, 0, acc, l);
      // -------- phase B: + c1 @ W_ih2^T, layer-2 cell --------
      wait2(a1g, t + 1, a1g, t + 1);
      gemm_slice(c1b + (size_t)wb * Bn * Hn + (size_t)arow * Hn + (lg << 3), smem, 65536, acc, l);
      unsigned short* h2w = h2b + (size_t)wb * Bn * Hn;
#pragma unroll
      for (int r = 0; r < 4; ++r) {
        float iv = sigm(acc[0][r] + b2g[0]);
        float ff = sigm(acc[1][r] + b2g[1]);
        float gv = tanh_(acc[2][r] + b2g[2]);
        float ov = sigm(acc[3][r] + b2g[3]);
        float c = ff * cst[r] + iv * gv;
        cst[r] = c;
        float h = ov * tanh_(c);
        store2_sc(h2w + (size_t)(myrow + r) * Hn + colj, f2bf(h));
      }
      arrive(&a2[sub], (unsigned)(t + 1));
    }
  }

  // epilogue: out[:, T-1]
  if (isL1) {
    wait2(a2g, Tn, a2g, Tn);
    out_duty(Tn - 1, sub, wv, l, h2b + (size_t)((Tn - 1) & 1) * Bn * Hn, smem, out);
  }
}

extern "C" void kernel_launch(void* const* d_in, const int* in_sizes, int n_in,
                              void* d_out, int out_size, void* d_ws, size_t ws_size,
                              hipStream_t stream) {
  const float* x     = (const float*)d_in[0];
  const float* W_ih1 = (const float*)d_in[1];
  const float* W_hh1 = (const float*)d_in[2];
  const float* b_ih1 = (const float*)d_in[3];
  const float* b_hh1 = (const float*)d_in[4];
  const float* W_ih2 = (const float*)d_in[5];
  const float* W_hh2 = (const float*)d_in[6];
  const float* b_ih2 = (const float*)d_in[7];
  const float* b_hh2 = (const float*)d_in[8];
  const float* W_fc  = (const float*)d_in[9];
  const float* b_fc  = (const float*)d_in[10];
  float* out = (float*)d_out;

  unsigned* flags = (unsigned*)d_ws;
  unsigned short* h1b = (unsigned short*)((char*)d_ws + 4096);
  unsigned short* c1b = h1b + 2 * Bn * Hn;
  unsigned short* h2b = c1b + 2 * Bn * Hn;

  // zero flags + state slabs every launch (graph-replay safe, deterministic)
  hipMemsetAsync(d_ws, 0, 4096 + (size_t)3 * 2 * Bn * Hn * sizeof(unsigned short), stream);

  (void)hipFuncSetAttribute((const void*)lstm2_kernel,
                            hipFuncAttributeMaxDynamicSharedMemorySize, 131072);

  lstm2_kernel<<<dim3(256), dim3(256), 131072, stream>>>(
      x, W_ih1, W_hh1, b_ih1, b_hh1, W_ih2, W_hh2, b_ih2, b_hh2, W_fc, b_fc,
      out, flags, h1b, c1b, h2b);
}

// Round 4
// 9748.679 us; speedup vs baseline: 4.4483x; 1.0785x over previous
//
#include <hip/hip_runtime.h>

// ---------------------------------------------------------------------------
// 2-layer LSTM (B=256, T=784, H=512, C=10), persistent kernel, round 4.
//
// Round-3 post-mortem: passed @10.5ms but MfmaUtil 4.7% -> per step the
// critical path was TWO flag hops (L1-A -> a1 -> L2-B -> a2 -> next A).
//
// Round-4: cross-population software pipeline, ONE hop per step.
//   Phase k:  L1-WGs compute layer-1 step t=k   (and FC out for t=k-2),
//             L2-WGs compute layer-2 step t=k-1 (both gemms fused).
//   All inter-WG dependencies become "previous phase" -> single group
//   barrier per phase (64 flags/group = 2 cache lines, 1 flag per lane).
//
// Dependency audit (all producers in phase k-1, consumers in phase k):
//   L2@k: c1[(k-1)&1] (L1@k-1), h2[(k-2)&1] (L2@k-1)
//   L1@k: h1[(k-1)&1] (L1@k-1); out_duty(k-2): h2[(k-2)&1] (L2@k-1)
//   WAR:  h1[k&1]/c1[k&1] last read @k-1; h2[(k-1)&1] last read @k-1.
//
// Coherence protocol (validated round 3): slab data via sc0+sc1 cache-bypass
// asm loads/stores; every wave drains vmcnt(0) before the arrive barrier
// (HW counter covers asm stores); lane-0 publishes flag with RELEASE(agent).
// `out` stores are also sc write-through so L2 never holds dirty lines and
// the release's cache maintenance stays cheap.
// ---------------------------------------------------------------------------

constexpr int Bn = 256;   // batch
constexpr int Tn = 784;   // timesteps
constexpr int Hn = 512;   // hidden
constexpr int Cn = 10;    // classes

typedef short s16x8 __attribute__((ext_vector_type(8)));
typedef float f32x4 __attribute__((ext_vector_type(4)));

__device__ __forceinline__ unsigned short f2bf(float f) {
  unsigned u = __float_as_uint(f);
  u += 0x7FFFu + ((u >> 16) & 1u);  // round-to-nearest-even
  return (unsigned short)(u >> 16);
}
__device__ __forceinline__ float bf2f(unsigned short s) {
  return __uint_as_float(((unsigned)s) << 16);
}
__device__ __forceinline__ float sigm(float v) { return 1.f / (1.f + __expf(-v)); }
__device__ __forceinline__ float tanh_(float v) {
  float vc = fminf(fmaxf(v, -15.f), 15.f);
  float e = __expf(2.f * vc);
  return (e - 1.f) / (e + 1.f);
}

// ---- system-scope (cache-bypassing) slab accessors ----
__device__ __forceinline__ s16x8 load16_sc(const unsigned short* p) {
  s16x8 r;
  asm volatile("global_load_dwordx4 %0, %1, off sc0 sc1"
               : "=v"(r) : "v"(p) : "memory");
  return r;
}
__device__ __forceinline__ void store2_sc(unsigned short* p, unsigned short v) {
  unsigned w = v;
  asm volatile("global_store_short %0, %1, off sc0 sc1"
               :: "v"(p), "v"(w) : "memory");
}
__device__ __forceinline__ void store4_sc(float* p, float v) {
  asm volatile("global_store_dword %0, %1, off sc0 sc1"
               :: "v"(p), "v"(v) : "memory");
}
// Drain all outstanding vmem (HW counter covers inline-asm ops) + pin sched.
__device__ __forceinline__ void vm0_fence() {
  asm volatile("s_waitcnt vmcnt(0)" ::: "memory");
  __builtin_amdgcn_sched_barrier(0);
}

// ---- phase barrier ----
__device__ __forceinline__ void arrive(unsigned* slot, unsigned v) {
  vm0_fence();
  __syncthreads();
  if (threadIdx.x == 0)
    __hip_atomic_store(slot, v, __ATOMIC_RELEASE, __HIP_MEMORY_SCOPE_AGENT);
}
// wave0: lane l polls gfl[l] >= th (64 flags = this group's L1+L2 WGs).
__device__ __forceinline__ void wait_group(const unsigned* gfl, int th) {
  if ((threadIdx.x >> 6) == 0 && th > 0) {
    const int l = threadIdx.x & 63;
    const unsigned* p = gfl + l;
    int guard = 0;
    for (;;) {
      int v = (int)__hip_atomic_load(p, __ATOMIC_RELAXED, __HIP_MEMORY_SCOPE_AGENT);
      if (__all(v >= th)) break;
      if (++guard > (1 << 18)) break;  // deadlock escape only
      __builtin_amdgcn_s_sleep(1);
    }
  }
  __syncthreads();
}

// 64x(4x16) gate-GEMM slice, K=512, 16x16x32 bf16 MFMA (A via sc loads,
// B weight slice in LDS, XOR-swizzled).
__device__ __forceinline__ void gemm_slice(const unsigned short* __restrict__ Abase,
                                           const char* smem, int ldsbase,
                                           f32x4* acc, int l) {
  const int lg = l >> 4, rA = l & 15, lx = l & 7;
  s16x8 af[16];
#pragma unroll
  for (int kc = 0; kc < 16; ++kc)
    af[kc] = load16_sc(Abase + kc * 32);
  vm0_fence();
#pragma unroll
  for (int kc = 0; kc < 16; ++kc) {
#pragma unroll
    for (int g = 0; g < 4; ++g) {
      int byte = ldsbase + (((g << 4) + rA) << 10) + ((((kc << 2) + lg) ^ lx) << 4);
      s16x8 bf = *(const s16x8*)(smem + byte);
      acc[g] = __builtin_amdgcn_mfma_f32_16x16x32_bf16(af[kc], bf, acc[g], 0, 0, 0);
    }
  }
}

// Fused double slice for L2: issue BOTH A-fragment load sets (h2 and c1),
// one vmcnt(0), then both MFMA passes. Halves exposed load latency.
__device__ __forceinline__ void gemm2_slice(const unsigned short* __restrict__ A1,
                                            const unsigned short* __restrict__ A2,
                                            const char* smem, f32x4* acc, int l) {
  const int lg = l >> 4, rA = l & 15, lx = l & 7;
  s16x8 a1[16], a2[16];
#pragma unroll
  for (int kc = 0; kc < 16; ++kc) a1[kc] = load16_sc(A1 + kc * 32);
#pragma unroll
  for (int kc = 0; kc < 16; ++kc) a2[kc] = load16_sc(A2 + kc * 32);
  vm0_fence();
#pragma unroll
  for (int kc = 0; kc < 16; ++kc) {
#pragma unroll
    for (int g = 0; g < 4; ++g) {
      int byte = (((g << 4) + rA) << 10) + ((((kc << 2) + lg) ^ lx) << 4);
      acc[g] = __builtin_amdgcn_mfma_f32_16x16x32_bf16(a1[kc], *(const s16x8*)(smem + byte), acc[g], 0, 0, 0);
    }
  }
#pragma unroll
  for (int kc = 0; kc < 16; ++kc) {
#pragma unroll
    for (int g = 0; g < 4; ++g) {
      int byte = 65536 + (((g << 4) + rA) << 10) + ((((kc << 2) + lg) ^ lx) << 4);
      acc[g] = __builtin_amdgcn_mfma_f32_16x16x32_bf16(a2[kc], *(const s16x8*)(smem + byte), acc[g], 0, 0, 0);
    }
  }
}

// Final FC for one timestep column (runs on L1 WGs, lagged two phases).
__device__ __forceinline__ void out_duty(int tt, int sub, int wv, int l,
                                         const unsigned short* __restrict__ h2buf,
                                         const char* smem, float* __restrict__ out) {
  const int b = (sub << 1) + (wv >> 1);
  const int cg = (wv & 1) * 5;
  s16x8 h8 = load16_sc(h2buf + (size_t)b * Hn + (l << 3));
  vm0_fence();
  const unsigned short* wf = (const unsigned short*)(smem + 65536);
  float rs[5];
#pragma unroll
  for (int c5 = 0; c5 < 5; ++c5) {
    s16x8 w8 = *(const s16x8*)(wf + (size_t)(cg + c5) * Hn + (l << 3));
    float s = 0.f;
#pragma unroll
    for (int i = 0; i < 8; ++i)
      s += bf2f((unsigned short)h8[i]) * bf2f((unsigned short)w8[i]);
    rs[c5] = s;
  }
#pragma unroll
  for (int c5 = 0; c5 < 5; ++c5) {
#pragma unroll
    for (int off = 32; off > 0; off >>= 1)
      rs[c5] += __shfl_xor(rs[c5], off);
  }
  if (l < 5) {
    float v = (l == 0) ? rs[0] : (l == 1) ? rs[1] : (l == 2) ? rs[2] : (l == 3) ? rs[3] : rs[4];
    v += ((const float*)(smem + 65536 + Cn * Hn * 2))[cg + l];
    store4_sc(out + (size_t)b * (Tn * Cn) + (size_t)tt * Cn + (cg + l), v);
  }
}

__global__ void __launch_bounds__(256, 1)
lstm2_kernel(const float* __restrict__ x,
             const float* __restrict__ W_ih1, const float* __restrict__ W_hh1,
             const float* __restrict__ b_ih1, const float* __restrict__ b_hh1,
             const float* __restrict__ W_ih2, const float* __restrict__ W_hh2,
             const float* __restrict__ b_ih2, const float* __restrict__ b_hh2,
             const float* __restrict__ W_fc, const float* __restrict__ b_fc,
             float* __restrict__ out,
             unsigned* __restrict__ flags,
             unsigned short* __restrict__ h1b,   // [2][B][H] bf16
             unsigned short* __restrict__ c1b,   // [2][B][H] bf16
             unsigned short* __restrict__ h2b)   // [2][B][H] bf16
{
  extern __shared__ char smem[];
  const int tid = threadIdx.x;
  const int wg = blockIdx.x;
  const int wv = tid >> 6;
  const int l = tid & 63;
  const bool isL1 = (wg < 128);
  const int sub = isL1 ? wg : (wg - 128);
  const int rb = (sub >> 5) << 6;   // 0,64,128,192
  const int js = (sub & 31) << 4;   // 0..496

  // ---- one-time: weight slices -> LDS bf16, XOR-swizzled on 16B chunks ----
  {
    const float* W0 = isL1 ? W_hh1 : W_hh2;
    for (int idx = tid * 4; idx < 64 * 512; idx += 1024) {
      int row = idx >> 9, k = idx & 511;                    // row = g*16 + c
      int n = ((row >> 4) << 9) + js + (row & 15);          // gate col
      float4 w = *(const float4*)(W0 + (size_t)n * Hn + k);
      short4 v = { (short)f2bf(w.x), (short)f2bf(w.y), (short)f2bf(w.z), (short)f2bf(w.w) };
      int byte = (row << 10) + ((((k >> 3) ^ (row & 7)) << 4)) + ((k & 7) << 1);
      *(short4*)(smem + byte) = v;
    }
    if (!isL1) {
      for (int idx = tid * 4; idx < 64 * 512; idx += 1024) {
        int row = idx >> 9, k = idx & 511;
        int n = ((row >> 4) << 9) + js + (row & 15);
        float4 w = *(const float4*)(W_ih2 + (size_t)n * Hn + k);
        short4 v = { (short)f2bf(w.x), (short)f2bf(w.y), (short)f2bf(w.z), (short)f2bf(w.w) };
        int byte = 65536 + (row << 10) + ((((k >> 3) ^ (row & 7)) << 4)) + ((k & 7) << 1);
        *(short4*)(smem + byte) = v;
      }
    } else {
      unsigned short* wf = (unsigned short*)(smem + 65536);
      for (int idx = tid; idx < Cn * Hn; idx += 256) wf[idx] = f2bf(W_fc[idx]);
      if (tid < Cn) ((float*)(smem + 65536 + Cn * Hn * 2))[tid] = b_fc[tid];
    }
  }
  __syncthreads();

  // per-lane constants
  float wih1g[4], b1g[4], b2g[4];
  {
    int col = js + (l & 15);
#pragma unroll
    for (int g = 0; g < 4; ++g) {
      int n = (g << 9) + col;
      if (isL1) { wih1g[g] = W_ih1[n]; b1g[g] = b_ih1[n] + b_hh1[n]; b2g[g] = 0.f; }
      else      { wih1g[g] = 0.f;      b1g[g] = 0.f;                 b2g[g] = b_ih2[n] + b_hh2[n]; }
    }
  }

  const int rA = l & 15, lg = l >> 4;
  const int arow = rb + (wv << 4) + rA;           // A-fragment row (batch)
  const int myrow = rb + (wv << 4) + (lg << 2);   // C/D first row (batch)
  const int colj = js + rA;                       // my hidden col

  // group-contiguous flags: 64 per group (32 L1 then 32 L2) = 2 cache lines
  const int g4 = sub >> 5;
  unsigned* gfl = flags + g4 * 64;
  unsigned* myfl = gfl + (isL1 ? 0 : 32) + (sub & 31);

  float cst[4] = {0.f, 0.f, 0.f, 0.f};  // persistent cell state (c1 or c2)

  for (int k = 0; k <= Tn; ++k) {
    wait_group(gfl, k);
    if (isL1) {
      if (k < Tn) {
        const int t = k, wb = t & 1, rbf = wb ^ 1;
        float xv[4];
#pragma unroll
        for (int r = 0; r < 4; ++r) xv[r] = x[(size_t)(myrow + r) * Tn + t];
        f32x4 acc[4];
#pragma unroll
        for (int g = 0; g < 4; ++g) acc[g] = f32x4{0.f, 0.f, 0.f, 0.f};
        gemm_slice(h1b + (size_t)rbf * Bn * Hn + (size_t)arow * Hn + (lg << 3), smem, 0, acc, l);
        unsigned short* h1w = h1b + (size_t)wb * Bn * Hn;
        unsigned short* c1w = c1b + (size_t)wb * Bn * Hn;
#pragma unroll
        for (int r = 0; r < 4; ++r) {
          float iv = sigm(acc[0][r] + xv[r] * wih1g[0] + b1g[0]);
          float ff = sigm(acc[1][r] + xv[r] * wih1g[1] + b1g[1]);
          float gv = tanh_(acc[2][r] + xv[r] * wih1g[2] + b1g[2]);
          float ov = sigm(acc[3][r] + xv[r] * wih1g[3] + b1g[3]);
          float c = ff * cst[r] + iv * gv;
          cst[r] = c;
          float h = ov * tanh_(c);
          size_t off = (size_t)(myrow + r) * Hn + colj;
          store2_sc(h1w + off, f2bf(h));
          store2_sc(c1w + off, f2bf(c));
        }
      }
      if (k >= 2)
        out_duty(k - 2, sub, wv, l, h2b + (size_t)((k - 2) & 1) * Bn * Hn, smem, out);
    } else {
      if (k >= 1) {
        const int t = k - 1, wb = t & 1, rbf = wb ^ 1;
        f32x4 acc[4];
#pragma unroll
        for (int g = 0; g < 4; ++g) acc[g] = f32x4{0.f, 0.f, 0.f, 0.f};
        gemm2_slice(h2b + (size_t)rbf * Bn * Hn + (size_t)arow * Hn + (lg << 3),
                    c1b + (size_t)wb  * Bn * Hn + (size_t)arow * Hn + (lg << 3),
                    smem, acc, l);
        unsigned short* h2w = h2b + (size_t)wb * Bn * Hn;
#pragma unroll
        for (int r = 0; r < 4; ++r) {
          float iv = sigm(acc[0][r] + b2g[0]);
          float ff = sigm(acc[1][r] + b2g[1]);
          float gv = tanh_(acc[2][r] + b2g[2]);
          float ov = sigm(acc[3][r] + b2g[3]);
          float c = ff * cst[r] + iv * gv;
          cst[r] = c;
          float h = ov * tanh_(c);
          store2_sc(h2w + (size_t)(myrow + r) * Hn + colj, f2bf(h));
        }
      }
    }
    arrive(myfl, (unsigned)(k + 1));
  }

  // epilogue: out[:, T-1] (h2(T-1) was written in phase Tn)
  if (isL1) {
    wait_group(gfl, Tn + 1);
    out_duty(Tn - 1, sub, wv, l, h2b + (size_t)((Tn - 1) & 1) * Bn * Hn, smem, out);
  }
}

extern "C" void kernel_launch(void* const* d_in, const int* in_sizes, int n_in,
                              void* d_out, int out_size, void* d_ws, size_t ws_size,
                              hipStream_t stream) {
  const float* x     = (const float*)d_in[0];
  const float* W_ih1 = (const float*)d_in[1];
  const float* W_hh1 = (const float*)d_in[2];
  const float* b_ih1 = (const float*)d_in[3];
  const float* b_hh1 = (const float*)d_in[4];
  const float* W_ih2 = (const float*)d_in[5];
  const float* W_hh2 = (const float*)d_in[6];
  const float* b_ih2 = (const float*)d_in[7];
  const float* b_hh2 = (const float*)d_in[8];
  const float* W_fc  = (const float*)d_in[9];
  const float* b_fc  = (const float*)d_in[10];
  float* out = (float*)d_out;

  unsigned* flags = (unsigned*)d_ws;
  unsigned short* h1b = (unsigned short*)((char*)d_ws + 4096);
  unsigned short* c1b = h1b + 2 * Bn * Hn;
  unsigned short* h2b = c1b + 2 * Bn * Hn;

  // zero flags + state slabs every launch (graph-replay safe, deterministic)
  hipMemsetAsync(d_ws, 0, 4096 + (size_t)3 * 2 * Bn * Hn * sizeof(unsigned short), stream);

  (void)hipFuncSetAttribute((const void*)lstm2_kernel,
                            hipFuncAttributeMaxDynamicSharedMemorySize, 131072);

  lstm2_kernel<<<dim3(256), dim3(256), 131072, stream>>>(
      x, W_ih1, W_hh1, b_ih1, b_hh1, W_ih2, W_hh2, b_ih2, b_hh2, W_fc, b_fc,
      out, flags, h1b, c1b, h2b);
}

// Round 5
// 8539.916 us; speedup vs baseline: 5.0779x; 1.1415x over previous
//
#include <hip/hip_runtime.h>

// ---------------------------------------------------------------------------
// 2-layer LSTM (B=256, T=784, H=512, C=10), persistent kernel, round 5.
//
// Round-4 post-mortem: one hop/step but still 12.4us/step (MfmaUtil 5%).
// Dominant residual: arrive()'s RELEASE(agent) flag store emits buffer_wbl2
// (L2 writeback walk) every phase on every WG; 32 WGs/XCD serialize on it.
// All cross-WG data here is sc0/sc1 write-through, so after the explicit
// vmcnt(0) drain there are no dirty L2 lines to publish -> the wbl2 is
// semantically dead. Round-5: flags become plain sc0/sc1 asm stores/loads.
// (Round-2's relaxed-flag failure was the missing vmcnt drain for asm data
// stores, fixed in round 3 and retained here.)
//
// Ordering proof: producer waves drain vmcnt(0) (data ACKed at MALL, the
// coherence point) -> syncthreads -> lane0 sc-stores flag to MALL. Consumer
// polls flag with sc loads from MALL; after observing it, issues data loads
// that also bypass L1/L2 to MALL -> must see the data. No cache maintenance
// anywhere in the loop.
//
// Structure (unchanged from round 4):
//   Phase k: L1-WGs: layer-1 step k + FC out for step k-2;
//            L2-WGs: layer-2 step k-1 (both gemms fused, single drain).
//   4 independent groups of (32 L1 + 32 L2) WGs; one 64-flag barrier per
//   phase per group (flags contiguous: 2 cache lines).
// Dependency audit (producers all in phase k-1): L2@k reads c1[(k-1)&1]
// (L1@k-1), h2[(k-2)&1] (L2@k-1); L1@k reads h1[(k-1)&1] (L1@k-1);
// out_duty(k-2) reads h2[(k-2)&1] (L2@k-1). WAR: h1/c1[k&1] last read @k-1,
// h2[(k-1)&1] last read @k-1.
// ---------------------------------------------------------------------------

constexpr int Bn = 256;   // batch
constexpr int Tn = 784;   // timesteps
constexpr int Hn = 512;   // hidden
constexpr int Cn = 10;    // classes

typedef short s16x8 __attribute__((ext_vector_type(8)));
typedef float f32x4 __attribute__((ext_vector_type(4)));

__device__ __forceinline__ unsigned short f2bf(float f) {
  unsigned u = __float_as_uint(f);
  u += 0x7FFFu + ((u >> 16) & 1u);  // round-to-nearest-even
  return (unsigned short)(u >> 16);
}
__device__ __forceinline__ float bf2f(unsigned short s) {
  return __uint_as_float(((unsigned)s) << 16);
}
__device__ __forceinline__ float sigm(float v) { return 1.f / (1.f + __expf(-v)); }
__device__ __forceinline__ float tanh_(float v) {
  float vc = fminf(fmaxf(v, -15.f), 15.f);
  float e = __expf(2.f * vc);
  return (e - 1.f) / (e + 1.f);
}

// ---- system-scope (cache-bypassing) accessors ----
__device__ __forceinline__ s16x8 load16_sc(const unsigned short* p) {
  s16x8 r;
  asm volatile("global_load_dwordx4 %0, %1, off sc0 sc1"
               : "=v"(r) : "v"(p) : "memory");
  return r;
}
__device__ __forceinline__ void store2_sc(unsigned short* p, unsigned short v) {
  unsigned w = v;
  asm volatile("global_store_short %0, %1, off sc0 sc1"
               :: "v"(p), "v"(w) : "memory");
}
__device__ __forceinline__ void store4_sc(float* p, float v) {
  asm volatile("global_store_dword %0, %1, off sc0 sc1"
               :: "v"(p), "v"(v) : "memory");
}
__device__ __forceinline__ unsigned load_flag_sc(const unsigned* p) {
  unsigned r;
  asm volatile("global_load_dword %0, %1, off sc0 sc1\n\t"
               "s_waitcnt vmcnt(0)"
               : "=v"(r) : "v"(p) : "memory");
  return r;
}
__device__ __forceinline__ void store_flag_sc(unsigned* p, unsigned v) {
  asm volatile("global_store_dword %0, %1, off sc0 sc1"
               :: "v"(p), "v"(v) : "memory");
}
// Drain all outstanding vmem (HW counter covers inline-asm ops) + pin sched.
__device__ __forceinline__ void vm0_fence() {
  asm volatile("s_waitcnt vmcnt(0)" ::: "memory");
  __builtin_amdgcn_sched_barrier(0);
}

// ---- phase barrier (no cache maintenance anywhere) ----
__device__ __forceinline__ void arrive(unsigned* slot, unsigned v) {
  vm0_fence();      // per-wave: all sc data stores ACKed at the MALL
  __syncthreads();  // all waves of this WG done
  if (threadIdx.x == 0) store_flag_sc(slot, v);
}
// wave0: lane l polls gfl[l] >= th (64 flags = this group's L1+L2 WGs).
__device__ __forceinline__ void wait_group(const unsigned* gfl, int th) {
  if ((threadIdx.x >> 6) == 0 && th > 0) {
    const unsigned* p = gfl + (threadIdx.x & 63);
    int guard = 0;
    for (;;) {
      int v = (int)load_flag_sc(p);
      if (__all(v >= th)) break;
      if (++guard > (1 << 18)) break;  // deadlock escape only
      __builtin_amdgcn_s_sleep(1);
    }
  }
  __syncthreads();
}

// 64x(4x16) gate-GEMM slice, K=512, 16x16x32 bf16 MFMA (A via sc loads,
// B weight slice in LDS, XOR-swizzled).
__device__ __forceinline__ void gemm_slice(const unsigned short* __restrict__ Abase,
                                           const char* smem, int ldsbase,
                                           f32x4* acc, int l) {
  const int lg = l >> 4, rA = l & 15, lx = l & 7;
  s16x8 af[16];
#pragma unroll
  for (int kc = 0; kc < 16; ++kc)
    af[kc] = load16_sc(Abase + kc * 32);
  vm0_fence();
#pragma unroll
  for (int kc = 0; kc < 16; ++kc) {
#pragma unroll
    for (int g = 0; g < 4; ++g) {
      int byte = ldsbase + (((g << 4) + rA) << 10) + ((((kc << 2) + lg) ^ lx) << 4);
      s16x8 bf = *(const s16x8*)(smem + byte);
      acc[g] = __builtin_amdgcn_mfma_f32_16x16x32_bf16(af[kc], bf, acc[g], 0, 0, 0);
    }
  }
}

// Fused double slice for L2: issue BOTH A-fragment load sets (h2 and c1),
// one vmcnt(0), then both MFMA passes. Halves exposed load latency.
__device__ __forceinline__ void gemm2_slice(const unsigned short* __restrict__ A1,
                                            const unsigned short* __restrict__ A2,
                                            const char* smem, f32x4* acc, int l) {
  const int lg = l >> 4, rA = l & 15, lx = l & 7;
  s16x8 a1[16], a2[16];
#pragma unroll
  for (int kc = 0; kc < 16; ++kc) a1[kc] = load16_sc(A1 + kc * 32);
#pragma unroll
  for (int kc = 0; kc < 16; ++kc) a2[kc] = load16_sc(A2 + kc * 32);
  vm0_fence();
#pragma unroll
  for (int kc = 0; kc < 16; ++kc) {
#pragma unroll
    for (int g = 0; g < 4; ++g) {
      int byte = (((g << 4) + rA) << 10) + ((((kc << 2) + lg) ^ lx) << 4);
      acc[g] = __builtin_amdgcn_mfma_f32_16x16x32_bf16(a1[kc], *(const s16x8*)(smem + byte), acc[g], 0, 0, 0);
    }
  }
#pragma unroll
  for (int kc = 0; kc < 16; ++kc) {
#pragma unroll
    for (int g = 0; g < 4; ++g) {
      int byte = 65536 + (((g << 4) + rA) << 10) + ((((kc << 2) + lg) ^ lx) << 4);
      acc[g] = __builtin_amdgcn_mfma_f32_16x16x32_bf16(a2[kc], *(const s16x8*)(smem + byte), acc[g], 0, 0, 0);
    }
  }
}

// Final FC for one timestep column (runs on L1 WGs, lagged two phases).
__device__ __forceinline__ void out_duty(int tt, int sub, int wv, int l,
                                         const unsigned short* __restrict__ h2buf,
                                         const char* smem, float* __restrict__ out) {
  const int b = (sub << 1) + (wv >> 1);
  const int cg = (wv & 1) * 5;
  s16x8 h8 = load16_sc(h2buf + (size_t)b * Hn + (l << 3));
  vm0_fence();
  const unsigned short* wf = (const unsigned short*)(smem + 65536);
  float rs[5];
#pragma unroll
  for (int c5 = 0; c5 < 5; ++c5) {
    s16x8 w8 = *(const s16x8*)(wf + (size_t)(cg + c5) * Hn + (l << 3));
    float s = 0.f;
#pragma unroll
    for (int i = 0; i < 8; ++i)
      s += bf2f((unsigned short)h8[i]) * bf2f((unsigned short)w8[i]);
    rs[c5] = s;
  }
#pragma unroll
  for (int c5 = 0; c5 < 5; ++c5) {
#pragma unroll
    for (int off = 32; off > 0; off >>= 1)
      rs[c5] += __shfl_xor(rs[c5], off);
  }
  if (l < 5) {
    float v = (l == 0) ? rs[0] : (l == 1) ? rs[1] : (l == 2) ? rs[2] : (l == 3) ? rs[3] : rs[4];
    v += ((const float*)(smem + 65536 + Cn * Hn * 2))[cg + l];
    store4_sc(out + (size_t)b * (Tn * Cn) + (size_t)tt * Cn + (cg + l), v);
  }
}

__global__ void __launch_bounds__(256, 1)
lstm2_kernel(const float* __restrict__ x,
             const float* __restrict__ W_ih1, const float* __restrict__ W_hh1,
             const float* __restrict__ b_ih1, const float* __restrict__ b_hh1,
             const float* __restrict__ W_ih2, const float* __restrict__ W_hh2,
             const float* __restrict__ b_ih2, const float* __restrict__ b_hh2,
             const float* __restrict__ W_fc, const float* __restrict__ b_fc,
             float* __restrict__ out,
             unsigned* __restrict__ flags,
             unsigned short* __restrict__ h1b,   // [2][B][H] bf16
             unsigned short* __restrict__ c1b,   // [2][B][H] bf16
             unsigned short* __restrict__ h2b)   // [2][B][H] bf16
{
  extern __shared__ char smem[];
  const int tid = threadIdx.x;
  const int wg = blockIdx.x;
  const int wv = tid >> 6;
  const int l = tid & 63;
  const bool isL1 = (wg < 128);
  const int sub = isL1 ? wg : (wg - 128);
  const int rb = (sub >> 5) << 6;   // 0,64,128,192
  const int js = (sub & 31) << 4;   // 0..496

  // ---- one-time: weight slices -> LDS bf16, XOR-swizzled on 16B chunks ----
  {
    const float* W0 = isL1 ? W_hh1 : W_hh2;
    for (int idx = tid * 4; idx < 64 * 512; idx += 1024) {
      int row = idx >> 9, k = idx & 511;                    // row = g*16 + c
      int n = ((row >> 4) << 9) + js + (row & 15);          // gate col
      float4 w = *(const float4*)(W0 + (size_t)n * Hn + k);
      short4 v = { (short)f2bf(w.x), (short)f2bf(w.y), (short)f2bf(w.z), (short)f2bf(w.w) };
      int byte = (row << 10) + ((((k >> 3) ^ (row & 7)) << 4)) + ((k & 7) << 1);
      *(short4*)(smem + byte) = v;
    }
    if (!isL1) {
      for (int idx = tid * 4; idx < 64 * 512; idx += 1024) {
        int row = idx >> 9, k = idx & 511;
        int n = ((row >> 4) << 9) + js + (row & 15);
        float4 w = *(const float4*)(W_ih2 + (size_t)n * Hn + k);
        short4 v = { (short)f2bf(w.x), (short)f2bf(w.y), (short)f2bf(w.z), (short)f2bf(w.w) };
        int byte = 65536 + (row << 10) + ((((k >> 3) ^ (row & 7)) << 4)) + ((k & 7) << 1);
        *(short4*)(smem + byte) = v;
      }
    } else {
      unsigned short* wf = (unsigned short*)(smem + 65536);
      for (int idx = tid; idx < Cn * Hn; idx += 256) wf[idx] = f2bf(W_fc[idx]);
      if (tid < Cn) ((float*)(smem + 65536 + Cn * Hn * 2))[tid] = b_fc[tid];
    }
  }
  __syncthreads();

  // per-lane constants
  float wih1g[4], b1g[4], b2g[4];
  {
    int col = js + (l & 15);
#pragma unroll
    for (int g = 0; g < 4; ++g) {
      int n = (g << 9) + col;
      if (isL1) { wih1g[g] = W_ih1[n]; b1g[g] = b_ih1[n] + b_hh1[n]; b2g[g] = 0.f; }
      else      { wih1g[g] = 0.f;      b1g[g] = 0.f;                 b2g[g] = b_ih2[n] + b_hh2[n]; }
    }
  }

  const int rA = l & 15, lg = l >> 4;
  const int arow = rb + (wv << 4) + rA;           // A-fragment row (batch)
  const int myrow = rb + (wv << 4) + (lg << 2);   // C/D first row (batch)
  const int colj = js + rA;                       // my hidden col

  // group-contiguous flags: 64 per group (32 L1 then 32 L2) = 2 cache lines
  const int g4 = sub >> 5;
  unsigned* gfl = flags + g4 * 64;
  unsigned* myfl = gfl + (isL1 ? 0 : 32) + (sub & 31);

  float cst[4] = {0.f, 0.f, 0.f, 0.f};  // persistent cell state (c1 or c2)

  for (int k = 0; k <= Tn; ++k) {
    wait_group(gfl, k);
    if (isL1) {
      if (k < Tn) {
        const int t = k, wb = t & 1, rbf = wb ^ 1;
        float xv[4];
#pragma unroll
        for (int r = 0; r < 4; ++r) xv[r] = x[(size_t)(myrow + r) * Tn + t];
        f32x4 acc[4];
#pragma unroll
        for (int g = 0; g < 4; ++g) acc[g] = f32x4{0.f, 0.f, 0.f, 0.f};
        gemm_slice(h1b + (size_t)rbf * Bn * Hn + (size_t)arow * Hn + (lg << 3), smem, 0, acc, l);
        unsigned short* h1w = h1b + (size_t)wb * Bn * Hn;
        unsigned short* c1w = c1b + (size_t)wb * Bn * Hn;
#pragma unroll
        for (int r = 0; r < 4; ++r) {
          float iv = sigm(acc[0][r] + xv[r] * wih1g[0] + b1g[0]);
          float ff = sigm(acc[1][r] + xv[r] * wih1g[1] + b1g[1]);
          float gv = tanh_(acc[2][r] + xv[r] * wih1g[2] + b1g[2]);
          float ov = sigm(acc[3][r] + xv[r] * wih1g[3] + b1g[3]);
          float c = ff * cst[r] + iv * gv;
          cst[r] = c;
          float h = ov * tanh_(c);
          size_t off = (size_t)(myrow + r) * Hn + colj;
          store2_sc(h1w + off, f2bf(h));
          store2_sc(c1w + off, f2bf(c));
        }
      }
      if (k >= 2)
        out_duty(k - 2, sub, wv, l, h2b + (size_t)((k - 2) & 1) * Bn * Hn, smem, out);
    } else {
      if (k >= 1) {
        const int t = k - 1, wb = t & 1, rbf = wb ^ 1;
        f32x4 acc[4];
#pragma unroll
        for (int g = 0; g < 4; ++g) acc[g] = f32x4{0.f, 0.f, 0.f, 0.f};
        gemm2_slice(h2b + (size_t)rbf * Bn * Hn + (size_t)arow * Hn + (lg << 3),
                    c1b + (size_t)wb  * Bn * Hn + (size_t)arow * Hn + (lg << 3),
                    smem, acc, l);
        unsigned short* h2w = h2b + (size_t)wb * Bn * Hn;
#pragma unroll
        for (int r = 0; r < 4; ++r) {
          float iv = sigm(acc[0][r] + b2g[0]);
          float ff = sigm(acc[1][r] + b2g[1]);
          float gv = tanh_(acc[2][r] + b2g[2]);
          float ov = sigm(acc[3][r] + b2g[3]);
          float c = ff * cst[r] + iv * gv;
          cst[r] = c;
          float h = ov * tanh_(c);
          store2_sc(h2w + (size_t)(myrow + r) * Hn + colj, f2bf(h));
        }
      }
    }
    arrive(myfl, (unsigned)(k + 1));
  }

  // epilogue: out[:, T-1] (h2(T-1) was written in phase Tn)
  if (isL1) {
    wait_group(gfl, Tn + 1);
    out_duty(Tn - 1, sub, wv, l, h2b + (size_t)((Tn - 1) & 1) * Bn * Hn, smem, out);
  }
}

extern "C" void kernel_launch(void* const* d_in, const int* in_sizes, int n_in,
                              void* d_out, int out_size, void* d_ws, size_t ws_size,
                              hipStream_t stream) {
  const float* x     = (const float*)d_in[0];
  const float* W_ih1 = (const float*)d_in[1];
  const float* W_hh1 = (const float*)d_in[2];
  const float* b_ih1 = (const float*)d_in[3];
  const float* b_hh1 = (const float*)d_in[4];
  const float* W_ih2 = (const float*)d_in[5];
  const float* W_hh2 = (const float*)d_in[6];
  const float* b_ih2 = (const float*)d_in[7];
  const float* b_hh2 = (const float*)d_in[8];
  const float* W_fc  = (const float*)d_in[9];
  const float* b_fc  = (const float*)d_in[10];
  float* out = (float*)d_out;

  unsigned* flags = (unsigned*)d_ws;
  unsigned short* h1b = (unsigned short*)((char*)d_ws + 4096);
  unsigned short* c1b = h1b + 2 * Bn * Hn;
  unsigned short* h2b = c1b + 2 * Bn * Hn;

  // zero flags + state slabs every launch (graph-replay safe, deterministic)
  hipMemsetAsync(d_ws, 0, 4096 + (size_t)3 * 2 * Bn * Hn * sizeof(unsigned short), stream);

  (void)hipFuncSetAttribute((const void*)lstm2_kernel,
                            hipFuncAttributeMaxDynamicSharedMemorySize, 131072);

  lstm2_kernel<<<dim3(256), dim3(256), 131072, stream>>>(
      x, W_ih1, W_hh1, b_ih1, b_hh1, W_ih2, W_hh2, b_ih2, b_hh2, W_fc, b_fc,
      out, flags, h1b, c1b, h2b);
}